// Round 12
// baseline (1584.616 us; speedup 1.0000x reference)
//
#include <hip/hip_runtime.h>
#include <math.h>

#define N_INIT 20000
#define LVLS   32
#define PP     1024
#define DD     64
#define DEE    128
#define N_TOT  (N_INIT + LVLS * PP)   // 52768
#define ND     (LVLS * PP)            // 32768 derived nodes
#define NBLK   512                    // 2 blocks/CU, co-residency proven r8-r11
#define NTHR   256
#define NPB    2                      // nodes per block per level
#define NTILES ((N_TOT + 63) / 64)    // 825 eval tiles

// ws layout:
// [0,256) ctl: acc_i[4]@0, acc_f@16, init_done@20, fin_done@24, lvl_cnt[32]@32
// [256, 256+ND*DD*4)  dstore (memset 0xFF each call: negative-NaN sentinel)
#define DSTORE_OFF 256

typedef unsigned long long ull;
union F2U { ull u; float2 f; };
#define SENT_MASK 0x8000000080000000ULL
#define SIGN_CLR  0x7FFFFFFF7FFFFFFFULL

// ---- device-coherent accessors (AGENT scope), proven r5-r11 ----
__device__ __forceinline__ int ldi(const int* p) {
    return __hip_atomic_load(p, __ATOMIC_RELAXED, __HIP_MEMORY_SCOPE_AGENT);
}
__device__ __forceinline__ float ldf(const float* p) {
    return __hip_atomic_load(p, __ATOMIC_RELAXED, __HIP_MEMORY_SCOPE_AGENT);
}
__device__ __forceinline__ ull ldull(const ull* p) {
    return __hip_atomic_load(p, __ATOMIC_RELAXED, __HIP_MEMORY_SCOPE_AGENT);
}
__device__ __forceinline__ void stull(ull* p, ull v) {
    __hip_atomic_store(p, v, __ATOMIC_RELAXED, __HIP_MEMORY_SCOPE_AGENT);
}
__device__ __forceinline__ void vm0() {
    asm volatile("s_waitcnt vmcnt(0)" ::: "memory");
}
__device__ __forceinline__ float softplusf(float x) {
    return fmaxf(x, 0.f) + log1pf(expf(-fabsf(x)));
}
// hybrid read of a published float2 (r11-proven): cached try, coherent spin fallback
__device__ __forceinline__ float2 ld_hyb(const ull* p) {
    F2U cv;
    cv.u = *p;
    if (cv.u & SENT_MASK) {
        cv.u = ldull(p);
        while (cv.u & SENT_MASK) {
            __builtin_amdgcn_s_sleep(1);
            cv.u = ldull(p);
        }
    }
    return cv.f;
}

__global__ __launch_bounds__(NTHR, 2) void persist8(
    const int* __restrict__ thax, const int* __restrict__ parents,
    const int* __restrict__ rules, const int* __restrict__ sel_mask,
    const int* __restrict__ good_mask, const float* __restrict__ init_table,
    const float* __restrict__ W_rule, const float* __restrict__ b_rule,
    const float* __restrict__ W1, const float* __restrict__ b1,
    const float* __restrict__ w2, const float* __restrict__ b2,
    char* __restrict__ ws, float* __restrict__ out)
{
    int*   acc_i     = (int*)ws;
    float* acc_f     = (float*)(ws + 16);
    int*   init_done = (int*)(ws + 20);
    int*   fin_done  = (int*)(ws + 24);
    int*   lvl_cnt   = (int*)(ws + 32);          // [32] published-node counters
    ull*   dstore_u  = (ull*)(ws + DSTORE_OFF);

    const int b = blockIdx.x, t = threadIdx.x;
    const int lane = t & 63, wv = t >> 6;

    __shared__ float    peL[NPB][2 * DD];        // 1 KB
    __shared__ float    partial[4][DD];          // 1 KB
    __shared__ float    sS[64][DD];              // 16 KB (eval)
    __shared__ float    logitL[64];
    __shared__ int      pidL[LVLS][2][2];        // 512 B: parent ids
    __shared__ int      plvL[LVLS][2][2];        // 512 B: parent derived-level or -1
    __shared__ int      snL[LVLS];               // counter snapshot
    __shared__ unsigned doneM[2];                // bit l: node (l, nb0+k) published
    __shared__ int      s_prog;

    // ---------------- phase 1: mask counts (r9 verbatim) ----------------
    {
        int idx = b * NTHR + t;
        bool v = idx < N_TOT;
        bool sel  = v && sel_mask[idx] > 0;
        bool good = sel && good_mask[idx] > 0;
        unsigned long long ms = __ballot(sel), mg = __ballot(good);
        if (lane == 0) {
            if (mg) atomicAdd(&acc_i[0], (int)__popcll(mg));
            if (ms) atomicAdd(&acc_i[1], (int)__popcll(ms));
        }
    }
    vm0();
    __syncthreads();
    if (t == 0) atomicAdd(init_done, 1);

    // ---------------- phase 2: out-of-order node execution ----------------
    const int nb0 = b * NPB;
    // precompute parent ids + levels for our 64 nodes
    for (int idx = t; idx < LVLS * 4; idx += NTHR) {
        int l = idx >> 2, slot = idx & 3;
        int pid = parents[((size_t)l * PP + nb0 + (slot >> 1)) * 2 + (slot & 1)];
        pidL[l][slot >> 1][slot & 1] = pid;
        plvL[l][slot >> 1][slot & 1] = pid < N_INIT ? -1 : ((pid - N_INIT) >> 10);
    }
    if (t == 0) { doneM[0] = 0u; doneM[1] = 0u; }
    __syncthreads();

    for (;;) {
        // pass start: snapshot counters (AGENT loads; stale => conservative)
        if (t < LVLS) snL[t] = ldi(&lvl_cnt[t]);
        if (t == 0) s_prog = 0;
        __syncthreads();
        unsigned dA = doneM[0], dB = doneM[1];
        if (dA == 0xFFFFFFFFu && dB == 0xFFFFFFFFu) break;

        for (int l = 0; l < LVLS; ++l) {
            bool doneA = (dA >> l) & 1u, doneB = (dB >> l) & 1u;
            if (doneA && doneB) continue;
            int a0 = plvL[l][0][0], a1 = plvL[l][0][1];
            int b0 = plvL[l][1][0], b1_ = plvL[l][1][1];
            bool readyA = (a0 < 0 || snL[a0] == PP) && (a1 < 0 || snL[a1] == PP);
            bool readyB = (b0 < 0 || snL[b0] == PP) && (b1_ < 0 || snL[b1_] == PP);
            bool procA = readyA && !doneA;
            bool procB = readyB && !doneB;
            if (!procA && !procB) continue;

            // gather parent rows for nodes being processed
            if (t < 128) {
                int row = t >> 5, j = t & 31;   // row 0,1 -> node 0; 2,3 -> node 1
                int k = row >> 1;
                if (k ? procB : procA) {
                    int pid = pidL[l][k][row & 1];
                    float2 v;
                    if (pid < N_INIT)
                        v = ((const float2*)init_table)[(size_t)thax[pid] * 32 + j];
                    else
                        v = ld_hyb(&dstore_u[(size_t)(pid - N_INIT) * 32 + j]);
                    ((float2*)&peL[k][(row & 1) * DD])[j] = v;
                }
            }
            __syncthreads();
            // compute (r9-proven math), guarded per node
            {
                const int nv = wv >> 1, half = wv & 1;
                if (nv ? procB : procA) {
                    const int ru = rules[l * PP + nb0 + nv];
                    const float4* __restrict__ W4 =
                        (const float4*)W_rule + (size_t)ru * 2048 + (size_t)half * 64 * 16;
                    const int q = lane & 15, r = lane >> 4;
                    const float* pk = &peL[nv][half * DD];
                    float4 acc = make_float4(0.f, 0.f, 0.f, 0.f);
#pragma unroll
                    for (int i = 0; i < 16; ++i) {
                        float4 w = W4[(i * 4 + r) * 16 + q];
                        float  s = pk[i * 4 + r];
                        acc.x = fmaf(s, w.x, acc.x);
                        acc.y = fmaf(s, w.y, acc.y);
                        acc.z = fmaf(s, w.z, acc.z);
                        acc.w = fmaf(s, w.w, acc.w);
                    }
#pragma unroll
                    for (int off = 16; off <= 32; off <<= 1) {
                        acc.x += __shfl_xor(acc.x, off, 64);
                        acc.y += __shfl_xor(acc.y, off, 64);
                        acc.z += __shfl_xor(acc.z, off, 64);
                        acc.w += __shfl_xor(acc.w, off, 64);
                    }
                    if (r == 0) *(float4*)&partial[wv][4 * q] = acc;
                }
            }
            __syncthreads();
            // publish (wave 0 only: t<64), sign-cleared sc1 stores
            if (t < 64) {
                const int nv = t >> 5;
                if (nv ? procB : procA) {
                    const int j2 = t & 31, jj = j2 * 2;
                    const int ru = rules[l * PP + nb0 + nv];
                    float h0 = partial[2 * nv][jj]     + partial[2 * nv + 1][jj]
                             + b_rule[ru * DD + jj];
                    float h1 = partial[2 * nv][jj + 1] + partial[2 * nv + 1][jj + 1]
                             + b_rule[ru * DD + jj + 1];
                    F2U cv;
                    cv.f.x = fmaxf(h0, 0.f);
                    cv.f.y = fmaxf(h1, 0.f);
                    cv.u &= SIGN_CLR;
                    stull(&dstore_u[((size_t)l * PP + nb0 + nv) * 32 + j2], cv.u);
                }
            }
            vm0();   // wave 0's publish stores reach coherence point
            if (t == 0) {
                atomicAdd(&lvl_cnt[l], (procA ? 1 : 0) + (procB ? 1 : 0));
                if (procA) doneM[0] |= (1u << l);
                if (procB) doneM[1] |= (1u << l);
                s_prog = 1;
            }
            __syncthreads();
            dA = doneM[0]; dB = doneM[1];
        }
        if (!s_prog) {           // no progress this pass: back off
#pragma unroll
            for (int i = 0; i < 8; ++i) __builtin_amdgcn_s_sleep(8);
        }
    }

    // ---------------- phase 3: gate on mask counts ----------------
    if (t == 0) { while (ldi(init_done) < NBLK) __builtin_amdgcn_s_sleep(1); }
    __syncthreads();
    const int ng = ldi(&acc_i[0]);
    const int ns = ldi(&acc_i[1]);
    const int nn = ns - ng;
    const float pos_w = ng > 0 ? 0.85f / (float)ng : 1.0f;
    const float neg_w = nn > 0 ? 0.15f / (float)nn : 1.0f;

    // ---------------- phase 4: eval + loss (r11 verbatim) ----------------
    const int g  = t & 31;
    const int n0 = t >> 5;
    const float4* __restrict__ W14 = (const float4*)W1;
    const float4 b1v = ((const float4*)b1)[g];
    const float4 w2v = ((const float4*)w2)[g];
    const float  b2v = b2[0];

    float loss = 0.f;
    int cp = 0, cn = 0;

    for (int tile = b; tile < NTILES; tile += NBLK) {
        const int base = tile * 64;
        const int nv = (N_TOT - base < 64) ? (N_TOT - base) : 64;
        for (int idx = t; idx < 64 * 32; idx += NTHR) {
            int n = idx >> 5, j = idx & 31;
            int node = base + n;
            float2 v = make_float2(0.f, 0.f);
            if (n < nv) {
                if (node < N_INIT)
                    v = ((const float2*)init_table)[(size_t)thax[node] * 32 + j];
                else
                    v = ld_hyb(&dstore_u[(size_t)(node - N_INIT) * 32 + j]);
            }
            ((float2*)sS[n])[j] = v;
        }
        __syncthreads();

        float4 a[8];
#pragma unroll
        for (int k = 0; k < 8; ++k) a[k] = b1v;
#pragma unroll
        for (int d4 = 0; d4 < 16; ++d4) {
            float4 w0  = W14[(d4 * 4 + 0) * 32 + g];
            float4 w1  = W14[(d4 * 4 + 1) * 32 + g];
            float4 w2q = W14[(d4 * 4 + 2) * 32 + g];
            float4 w3  = W14[(d4 * 4 + 3) * 32 + g];
#pragma unroll
            for (int k = 0; k < 8; ++k) {
                float4 s = ((const float4*)sS[n0 + 8 * k])[d4];
                a[k].x = fmaf(s.x, w0.x, a[k].x); a[k].y = fmaf(s.x, w0.y, a[k].y);
                a[k].z = fmaf(s.x, w0.z, a[k].z); a[k].w = fmaf(s.x, w0.w, a[k].w);
                a[k].x = fmaf(s.y, w1.x, a[k].x); a[k].y = fmaf(s.y, w1.y, a[k].y);
                a[k].z = fmaf(s.y, w1.z, a[k].z); a[k].w = fmaf(s.y, w1.w, a[k].w);
                a[k].x = fmaf(s.z, w2q.x, a[k].x); a[k].y = fmaf(s.z, w2q.y, a[k].y);
                a[k].z = fmaf(s.z, w2q.z, a[k].z); a[k].w = fmaf(s.z, w2q.w, a[k].w);
                a[k].x = fmaf(s.w, w3.x, a[k].x); a[k].y = fmaf(s.w, w3.y, a[k].y);
                a[k].z = fmaf(s.w, w3.z, a[k].z); a[k].w = fmaf(s.w, w3.w, a[k].w);
            }
        }
        float p[8];
#pragma unroll
        for (int k = 0; k < 8; ++k) {
            p[k] = fmaxf(a[k].x, 0.f) * w2v.x + fmaxf(a[k].y, 0.f) * w2v.y +
                   fmaxf(a[k].z, 0.f) * w2v.z + fmaxf(a[k].w, 0.f) * w2v.w;
#pragma unroll
            for (int off = 1; off < 32; off <<= 1)
                p[k] += __shfl_xor(p[k], off, 32);
        }
        if (g == 0) {
#pragma unroll
            for (int k = 0; k < 8; ++k)
                logitL[n0 + 8 * k] = p[k] + b2v;
        }
        __syncthreads();

        if (t < 64) {
            int node = base + t;
            bool valid = t < nv;
            float lg = logitL[t];
            bool sel  = valid && sel_mask[node] > 0;
            bool good = sel && good_mask[node] > 0;
            float bce = softplusf(lg) - lg * (good ? 1.f : 0.f);
            float w   = (good ? pos_w : neg_w) * (sel ? 1.f : 0.f);
            loss += valid ? w * bce : 0.f;
            cp += (good && lg >= 0.f) ? 1 : 0;
            cn += (sel && !good && lg < 0.f) ? 1 : 0;
        }
        __syncthreads();
    }

    // ---------------- phase 5: reduce + finalize (r9 verbatim) ----------------
    if (t < 64) {
        float c = loss;
        int cpp = cp, cnn = cn;
#pragma unroll
        for (int off = 32; off; off >>= 1) {
            c   += __shfl_down(c, off, 64);
            cpp += __shfl_down(cpp, off, 64);
            cnn += __shfl_down(cnn, off, 64);
        }
        if (t == 0) {
            atomicAdd(acc_f, c);
            if (cpp) atomicAdd(&acc_i[2], cpp);
            if (cnn) atomicAdd(&acc_i[3], cnn);
            vm0();
            int d = atomicAdd(fin_done, 1);
            if (d == NBLK - 1) {
                int ng2 = ldi(&acc_i[0]);
                int ns2 = ldi(&acc_i[1]);
                int cp2 = ldi(&acc_i[2]);
                int cn2 = ldi(&acc_i[3]);
                float lf = ldf(acc_f);
                int nn2 = ns2 - ng2;
                out[0] = lf;
                out[1] = ng2 > 0 ? (float)cp2 / (float)ng2 : 1.0f;
                out[2] = nn2 > 0 ? (float)cn2 / (float)nn2 : 1.0f;
            }
        }
    }
}

extern "C" void kernel_launch(void* const* d_in, const int* in_sizes, int n_in,
                              void* d_out, int out_size, void* d_ws, size_t ws_size,
                              hipStream_t stream) {
    const int*   thax       = (const int*)d_in[0];
    const int*   parents    = (const int*)d_in[1];
    const int*   rules      = (const int*)d_in[2];
    const int*   sel_mask   = (const int*)d_in[3];
    const int*   good_mask  = (const int*)d_in[4];
    const float* init_table = (const float*)d_in[5];
    const float* W_rule     = (const float*)d_in[6];
    const float* b_rule     = (const float*)d_in[7];
    const float* W1         = (const float*)d_in[8];
    const float* b1         = (const float*)d_in[9];
    const float* w2         = (const float*)d_in[10];
    const float* b2         = (const float*)d_in[11];

    // ctl (incl. lvl_cnt) -> 0 ; dstore -> 0xFF (negative-NaN sentinel)
    hipMemsetAsync(d_ws, 0, 256, stream);
    hipMemsetAsync((char*)d_ws + DSTORE_OFF, 0xFF, (size_t)ND * DD * 4, stream);

    persist8<<<NBLK, NTHR, 0, stream>>>(
        thax, parents, rules, sel_mask, good_mask, init_table,
        W_rule, b_rule, W1, b1, w2, b2,
        (char*)d_ws, (float*)d_out);
}

// Round 13
// 194.886 us; speedup vs baseline: 8.1310x; 8.1310x over previous
//
#include <hip/hip_runtime.h>
#include <math.h>

#define N_INIT 20000
#define LVLS   32
#define PP     1024
#define DD     64
#define DEE    128
#define N_TOT  (N_INIT + LVLS * PP)   // 52768
#define ND     (LVLS * PP)            // 32768 derived nodes
#define NBLK   512                    // 2 blocks/CU, co-residency proven r8-r12
#define NTHR   256
#define NPB    2                      // nodes per block per level
#define NTILES ((N_TOT + 63) / 64)    // 825 eval tiles

// ws layout:
// [0,256) ctl: acc_i[4]@0, acc_f@16, init_done@20, fin_done@24
// [256, 256+ND*DD*4)  dstore (memset 0xFF each call: negative-NaN sentinel)
#define DSTORE_OFF 256

typedef unsigned long long ull;
union F2U { ull u; float2 f; };
#define SENT_MASK 0x8000000080000000ULL
#define SIGN_CLR  0x7FFFFFFF7FFFFFFFULL

// ---- device-coherent accessors (AGENT scope), proven r5-r12 ----
__device__ __forceinline__ int ldi(const int* p) {
    return __hip_atomic_load(p, __ATOMIC_RELAXED, __HIP_MEMORY_SCOPE_AGENT);
}
__device__ __forceinline__ float ldf(const float* p) {
    return __hip_atomic_load(p, __ATOMIC_RELAXED, __HIP_MEMORY_SCOPE_AGENT);
}
__device__ __forceinline__ ull ldull(const ull* p) {
    return __hip_atomic_load(p, __ATOMIC_RELAXED, __HIP_MEMORY_SCOPE_AGENT);
}
__device__ __forceinline__ void stull(ull* p, ull v) {
    __hip_atomic_store(p, v, __ATOMIC_RELAXED, __HIP_MEMORY_SCOPE_AGENT);
}
__device__ __forceinline__ void vm0() {
    asm volatile("s_waitcnt vmcnt(0)" ::: "memory");
}
__device__ __forceinline__ float softplusf(float x) {
    return fmaxf(x, 0.f) + log1pf(expf(-fabsf(x)));
}
// blocking read of a published float2 (r11-proven): cached try, coherent spin fallback
__device__ __forceinline__ float2 ld_hyb(const ull* p) {
    F2U cv;
    cv.u = *p;
    if (cv.u & SENT_MASK) {
        cv.u = ldull(p);
        while (cv.u & SENT_MASK) {
            __builtin_amdgcn_s_sleep(1);
            cv.u = ldull(p);
        }
    }
    return cv.f;
}

__global__ __launch_bounds__(NTHR, 2) void persist9(
    const int* __restrict__ thax, const int* __restrict__ parents,
    const int* __restrict__ rules, const int* __restrict__ sel_mask,
    const int* __restrict__ good_mask, const float* __restrict__ init_table,
    const float* __restrict__ W_rule, const float* __restrict__ b_rule,
    const float* __restrict__ W1, const float* __restrict__ b1,
    const float* __restrict__ w2, const float* __restrict__ b2,
    char* __restrict__ ws, float* __restrict__ out)
{
    int*   acc_i     = (int*)ws;
    float* acc_f     = (float*)(ws + 16);
    int*   init_done = (int*)(ws + 20);
    int*   fin_done  = (int*)(ws + 24);
    ull*   dstore_u  = (ull*)(ws + DSTORE_OFF);

    const int b = blockIdx.x, t = threadIdx.x;
    const int lane = t & 63, wv = t >> 6;

    __shared__ float    peL[NPB][2 * DD];   // 1 KB
    __shared__ float    partial[4][DD];     // 1 KB
    __shared__ float    sS[64][DD];         // 16 KB (eval)
    __shared__ float    logitL[64];
    __shared__ int      pidL[LVLS][2][2];   // 512 B
    __shared__ int      badW[2];            // per-node sentinel-seen flags
    __shared__ unsigned doneM[2];
    __shared__ int      s_prog;

    // ---------------- phase 1: mask counts (r9 verbatim) ----------------
    {
        int idx = b * NTHR + t;
        bool v = idx < N_TOT;
        bool sel  = v && sel_mask[idx] > 0;
        bool good = sel && good_mask[idx] > 0;
        unsigned long long ms = __ballot(sel), mg = __ballot(good);
        if (lane == 0) {
            if (mg) atomicAdd(&acc_i[0], (int)__popcll(mg));
            if (ms) atomicAdd(&acc_i[1], (int)__popcll(ms));
        }
    }
    vm0();
    __syncthreads();
    if (t == 0) atomicAdd(init_done, 1);

    // ---------------- phase 2: speculative sweep + cleanup passes ----------------
    const int nb0 = b * NPB;
    for (int idx = t; idx < LVLS * 4; idx += NTHR) {
        int l = idx >> 2, slot = idx & 3;
        pidL[l][slot >> 1][slot & 1] =
            parents[((size_t)l * PP + nb0 + (slot >> 1)) * 2 + (slot & 1)];
    }
    if (t == 0) { badW[0] = 0; badW[1] = 0; }
    __syncthreads();
    // prologue: gather level 0 (parents all < N_INIT by construction)
    if (t < 128) {
        int row = t >> 5, j = t & 31;
        int pid = pidL[0][row >> 1][row & 1];
        float2 v = ((const float2*)init_table)[(size_t)thax[pid] * 32 + j];
        ((float2*)&peL[row >> 1][(row & 1) * DD])[j] = v;
    }
    __syncthreads();

    unsigned dA = 0, dB = 0;
    // ---- pass 1: pipelined, non-blocking (defers nodes with unready parents) ----
    for (int l = 0; l < LVLS; ++l) {
        bool procA = badW[0] == 0;
        bool procB = badW[1] == 0;
        // compute (r9-proven math), guarded per node
        {
            const int nv = wv >> 1, half = wv & 1;
            if (nv ? procB : procA) {
                const int ru = rules[l * PP + nb0 + nv];
                const float4* __restrict__ W4 =
                    (const float4*)W_rule + (size_t)ru * 2048 + (size_t)half * 64 * 16;
                const int q = lane & 15, r = lane >> 4;
                const float* pk = &peL[nv][half * DD];
                float4 acc = make_float4(0.f, 0.f, 0.f, 0.f);
#pragma unroll
                for (int i = 0; i < 16; ++i) {
                    float4 w = W4[(i * 4 + r) * 16 + q];
                    float  s = pk[i * 4 + r];
                    acc.x = fmaf(s, w.x, acc.x);
                    acc.y = fmaf(s, w.y, acc.y);
                    acc.z = fmaf(s, w.z, acc.z);
                    acc.w = fmaf(s, w.w, acc.w);
                }
#pragma unroll
                for (int off = 16; off <= 32; off <<= 1) {
                    acc.x += __shfl_xor(acc.x, off, 64);
                    acc.y += __shfl_xor(acc.y, off, 64);
                    acc.z += __shfl_xor(acc.z, off, 64);
                    acc.w += __shfl_xor(acc.w, off, 64);
                }
                if (r == 0) *(float4*)&partial[wv][4 * q] = acc;
            }
        }
        if (procA) dA |= (1u << l);
        if (procB) dB |= (1u << l);
        __syncthreads();                       // partial ready; peL consumed
        // publish level l (guarded) ∥ speculative gather level l+1 + ballot
        if (t < 64) {
            const int nv = t >> 5;
            if (nv ? procB : procA) {
                const int j2 = t & 31, jj = j2 * 2;
                const int ru = rules[l * PP + nb0 + nv];
                float h0 = partial[2 * nv][jj]     + partial[2 * nv + 1][jj]
                         + b_rule[ru * DD + jj];
                float h1 = partial[2 * nv][jj + 1] + partial[2 * nv + 1][jj + 1]
                         + b_rule[ru * DD + jj + 1];
                F2U cv;
                cv.f.x = fmaxf(h0, 0.f);
                cv.f.y = fmaxf(h1, 0.f);
                cv.u &= SIGN_CLR;
                stull(&dstore_u[((size_t)l * PP + nb0 + nv) * 32 + j2], cv.u);
            }
        }
        if (l + 1 < LVLS && t < 128) {
            int row = t >> 5, j = t & 31, k = row >> 1;
            int pid = pidL[l + 1][k][row & 1];
            bool bad = false;
            F2U cv;
            if (pid < N_INIT) {
                cv.f = ((const float2*)init_table)[(size_t)thax[pid] * 32 + j];
            } else {
                cv.u = ldull(&dstore_u[(size_t)(pid - N_INIT) * 32 + j]);
                bad = (cv.u & SENT_MASK) != 0ull;
            }
            ((float2*)&peL[k][(row & 1) * DD])[j] = cv.f;
            unsigned long long m = __ballot(bad);
            if (lane == 0) badW[wv] = (m != 0ull) ? 1 : 0;   // wave0->A, wave1->B
        }
        __syncthreads();                       // badW + peL ready for next iter
    }
    if (t == 0) { doneM[0] = dA; doneM[1] = dB; }

    // ---- cleanup passes: only pending nodes, non-blocking tries ----
    for (;;) {
        __syncthreads();
        unsigned pA = ~doneM[0], pB = ~doneM[1];
        if (!(pA | pB)) break;
        if (t == 0) s_prog = 0;
        __syncthreads();
        for (int l = 0; l < LVLS; ++l) {
            bool wantA = (pA >> l) & 1u, wantB = (pB >> l) & 1u;
            if (!wantA && !wantB) continue;
            // try-gather (guarded) + ballot
            if (t < 128) {
                int row = t >> 5, j = t & 31, k = row >> 1;
                bool bad = false;
                if (k ? wantB : wantA) {
                    int pid = pidL[l][k][row & 1];
                    F2U cv;
                    if (pid < N_INIT) {
                        cv.f = ((const float2*)init_table)[(size_t)thax[pid] * 32 + j];
                    } else {
                        cv.u = ldull(&dstore_u[(size_t)(pid - N_INIT) * 32 + j]);
                        bad = (cv.u & SENT_MASK) != 0ull;
                    }
                    ((float2*)&peL[k][(row & 1) * DD])[j] = cv.f;
                }
                unsigned long long m = __ballot(bad);
                if (lane == 0) badW[wv] = (m != 0ull) ? 1 : 0;
            }
            __syncthreads();
            bool procA = wantA && badW[0] == 0;
            bool procB = wantB && badW[1] == 0;
            if (procA || procB) {
                const int nv = wv >> 1, half = wv & 1;
                if (nv ? procB : procA) {
                    const int ru = rules[l * PP + nb0 + nv];
                    const float4* __restrict__ W4 =
                        (const float4*)W_rule + (size_t)ru * 2048 + (size_t)half * 64 * 16;
                    const int q = lane & 15, r = lane >> 4;
                    const float* pk = &peL[nv][half * DD];
                    float4 acc = make_float4(0.f, 0.f, 0.f, 0.f);
#pragma unroll
                    for (int i = 0; i < 16; ++i) {
                        float4 w = W4[(i * 4 + r) * 16 + q];
                        float  s = pk[i * 4 + r];
                        acc.x = fmaf(s, w.x, acc.x);
                        acc.y = fmaf(s, w.y, acc.y);
                        acc.z = fmaf(s, w.z, acc.z);
                        acc.w = fmaf(s, w.w, acc.w);
                    }
#pragma unroll
                    for (int off = 16; off <= 32; off <<= 1) {
                        acc.x += __shfl_xor(acc.x, off, 64);
                        acc.y += __shfl_xor(acc.y, off, 64);
                        acc.z += __shfl_xor(acc.z, off, 64);
                        acc.w += __shfl_xor(acc.w, off, 64);
                    }
                    if (r == 0) *(float4*)&partial[wv][4 * q] = acc;
                }
            }
            __syncthreads();
            if (t < 64) {
                const int nv = t >> 5;
                if (nv ? procB : procA) {
                    const int j2 = t & 31, jj = j2 * 2;
                    const int ru = rules[l * PP + nb0 + nv];
                    float h0 = partial[2 * nv][jj]     + partial[2 * nv + 1][jj]
                             + b_rule[ru * DD + jj];
                    float h1 = partial[2 * nv][jj + 1] + partial[2 * nv + 1][jj + 1]
                             + b_rule[ru * DD + jj + 1];
                    F2U cv;
                    cv.f.x = fmaxf(h0, 0.f);
                    cv.f.y = fmaxf(h1, 0.f);
                    cv.u &= SIGN_CLR;
                    stull(&dstore_u[((size_t)l * PP + nb0 + nv) * 32 + j2], cv.u);
                }
            }
            if (t == 0) {
                if (procA) doneM[0] |= (1u << l);
                if (procB) doneM[1] |= (1u << l);
                if (procA || procB) s_prog = 1;
            }
            __syncthreads();
        }
        if (!s_prog) {
#pragma unroll
            for (int i = 0; i < 4; ++i) __builtin_amdgcn_s_sleep(8);
        }
    }

    // ---------------- phase 3: gate on mask counts ----------------
    if (t == 0) { while (ldi(init_done) < NBLK) __builtin_amdgcn_s_sleep(1); }
    __syncthreads();
    const int ng = ldi(&acc_i[0]);
    const int ns = ldi(&acc_i[1]);
    const int nn = ns - ng;
    const float pos_w = ng > 0 ? 0.85f / (float)ng : 1.0f;
    const float neg_w = nn > 0 ? 0.15f / (float)nn : 1.0f;

    // ---------------- phase 4: eval + loss (r11 verbatim) ----------------
    const int g  = t & 31;
    const int n0 = t >> 5;
    const float4* __restrict__ W14 = (const float4*)W1;
    const float4 b1v = ((const float4*)b1)[g];
    const float4 w2v = ((const float4*)w2)[g];
    const float  b2v = b2[0];

    float loss = 0.f;
    int cp = 0, cn = 0;

    for (int tile = b; tile < NTILES; tile += NBLK) {
        const int base = tile * 64;
        const int nv = (N_TOT - base < 64) ? (N_TOT - base) : 64;
        for (int idx = t; idx < 64 * 32; idx += NTHR) {
            int n = idx >> 5, j = idx & 31;
            int node = base + n;
            float2 v = make_float2(0.f, 0.f);
            if (n < nv) {
                if (node < N_INIT)
                    v = ((const float2*)init_table)[(size_t)thax[node] * 32 + j];
                else
                    v = ld_hyb(&dstore_u[(size_t)(node - N_INIT) * 32 + j]);
            }
            ((float2*)sS[n])[j] = v;
        }
        __syncthreads();

        float4 a[8];
#pragma unroll
        for (int k = 0; k < 8; ++k) a[k] = b1v;
#pragma unroll
        for (int d4 = 0; d4 < 16; ++d4) {
            float4 w0  = W14[(d4 * 4 + 0) * 32 + g];
            float4 w1  = W14[(d4 * 4 + 1) * 32 + g];
            float4 w2q = W14[(d4 * 4 + 2) * 32 + g];
            float4 w3  = W14[(d4 * 4 + 3) * 32 + g];
#pragma unroll
            for (int k = 0; k < 8; ++k) {
                float4 s = ((const float4*)sS[n0 + 8 * k])[d4];
                a[k].x = fmaf(s.x, w0.x, a[k].x); a[k].y = fmaf(s.x, w0.y, a[k].y);
                a[k].z = fmaf(s.x, w0.z, a[k].z); a[k].w = fmaf(s.x, w0.w, a[k].w);
                a[k].x = fmaf(s.y, w1.x, a[k].x); a[k].y = fmaf(s.y, w1.y, a[k].y);
                a[k].z = fmaf(s.y, w1.z, a[k].z); a[k].w = fmaf(s.y, w1.w, a[k].w);
                a[k].x = fmaf(s.z, w2q.x, a[k].x); a[k].y = fmaf(s.z, w2q.y, a[k].y);
                a[k].z = fmaf(s.z, w2q.z, a[k].z); a[k].w = fmaf(s.z, w2q.w, a[k].w);
                a[k].x = fmaf(s.w, w3.x, a[k].x); a[k].y = fmaf(s.w, w3.y, a[k].y);
                a[k].z = fmaf(s.w, w3.z, a[k].z); a[k].w = fmaf(s.w, w3.w, a[k].w);
            }
        }
        float p[8];
#pragma unroll
        for (int k = 0; k < 8; ++k) {
            p[k] = fmaxf(a[k].x, 0.f) * w2v.x + fmaxf(a[k].y, 0.f) * w2v.y +
                   fmaxf(a[k].z, 0.f) * w2v.z + fmaxf(a[k].w, 0.f) * w2v.w;
#pragma unroll
            for (int off = 1; off < 32; off <<= 1)
                p[k] += __shfl_xor(p[k], off, 32);
        }
        if (g == 0) {
#pragma unroll
            for (int k = 0; k < 8; ++k)
                logitL[n0 + 8 * k] = p[k] + b2v;
        }
        __syncthreads();

        if (t < 64) {
            int node = base + t;
            bool valid = t < nv;
            float lg = logitL[t];
            bool sel  = valid && sel_mask[node] > 0;
            bool good = sel && good_mask[node] > 0;
            float bce = softplusf(lg) - lg * (good ? 1.f : 0.f);
            float w   = (good ? pos_w : neg_w) * (sel ? 1.f : 0.f);
            loss += valid ? w * bce : 0.f;
            cp += (good && lg >= 0.f) ? 1 : 0;
            cn += (sel && !good && lg < 0.f) ? 1 : 0;
        }
        __syncthreads();
    }

    // ---------------- phase 5: reduce + finalize (r9 verbatim) ----------------
    if (t < 64) {
        float c = loss;
        int cpp = cp, cnn = cn;
#pragma unroll
        for (int off = 32; off; off >>= 1) {
            c   += __shfl_down(c, off, 64);
            cpp += __shfl_down(cpp, off, 64);
            cnn += __shfl_down(cnn, off, 64);
        }
        if (t == 0) {
            atomicAdd(acc_f, c);
            if (cpp) atomicAdd(&acc_i[2], cpp);
            if (cnn) atomicAdd(&acc_i[3], cnn);
            vm0();
            int d = atomicAdd(fin_done, 1);
            if (d == NBLK - 1) {
                int ng2 = ldi(&acc_i[0]);
                int ns2 = ldi(&acc_i[1]);
                int cp2 = ldi(&acc_i[2]);
                int cn2 = ldi(&acc_i[3]);
                float lf = ldf(acc_f);
                int nn2 = ns2 - ng2;
                out[0] = lf;
                out[1] = ng2 > 0 ? (float)cp2 / (float)ng2 : 1.0f;
                out[2] = nn2 > 0 ? (float)cn2 / (float)nn2 : 1.0f;
            }
        }
    }
}

extern "C" void kernel_launch(void* const* d_in, const int* in_sizes, int n_in,
                              void* d_out, int out_size, void* d_ws, size_t ws_size,
                              hipStream_t stream) {
    const int*   thax       = (const int*)d_in[0];
    const int*   parents    = (const int*)d_in[1];
    const int*   rules      = (const int*)d_in[2];
    const int*   sel_mask   = (const int*)d_in[3];
    const int*   good_mask  = (const int*)d_in[4];
    const float* init_table = (const float*)d_in[5];
    const float* W_rule     = (const float*)d_in[6];
    const float* b_rule     = (const float*)d_in[7];
    const float* W1         = (const float*)d_in[8];
    const float* b1         = (const float*)d_in[9];
    const float* w2         = (const float*)d_in[10];
    const float* b2         = (const float*)d_in[11];

    // ctl -> 0 ; dstore -> 0xFF (negative-NaN sentinel, sign bit 1)
    hipMemsetAsync(d_ws, 0, 256, stream);
    hipMemsetAsync((char*)d_ws + DSTORE_OFF, 0xFF, (size_t)ND * DD * 4, stream);

    persist9<<<NBLK, NTHR, 0, stream>>>(
        thax, parents, rules, sel_mask, good_mask, init_table,
        W_rule, b_rule, W1, b1, w2, b2,
        (char*)d_ws, (float*)d_out);
}